// Round 2
// baseline (228.552 us; speedup 1.0000x reference)
//
#include <hip/hip_runtime.h>
#include <hip/hip_bf16.h>

#define NN 4096
#define MM 8192
#define GG 8
#define HH 128
#define NDD 16
#define EE 131072

// ---------------- init: zero deg / sums / cnt ----------------
__global__ void k_init(int* deg, float* sums, float* cnt) {
    int i = blockIdx.x * 256 + threadIdx.x;
    if (i < NN) deg[i] = 0;
    if (i < GG * HH) sums[i] = 0.f;
    if (i < GG) cnt[i] = 0.f;
}

// ---------------- node_emb_base = x @ W_node + b_node ----------------
__global__ __launch_bounds__(128) void k_node_emb(const float* __restrict__ x,
                                                  const float* __restrict__ Wn,
                                                  const float* __restrict__ bn,
                                                  float* __restrict__ out) {
    __shared__ float At[8][NDD];
    int r0 = blockIdx.x * 8;
    int t = threadIdx.x;  // 128
    At[t / NDD][t % NDD] = x[(r0 + t / NDD) * NDD + (t % NDD)];
    __syncthreads();
    float bias = bn[t];
    float acc[8];
#pragma unroll
    for (int r = 0; r < 8; r++) acc[r] = bias;
    for (int k = 0; k < NDD; k++) {
        float w = Wn[k * HH + t];
#pragma unroll
        for (int r = 0; r < 8; r++) acc[r] += At[r][k] * w;
    }
#pragma unroll
    for (int r = 0; r < 8; r++) out[(r0 + r) * HH + t] = acc[r];
}

// ---------------- cond pooling partial sums (LDS staged) ----------------
__global__ __launch_bounds__(256) void k_cond(const float* __restrict__ obj_x,
                                              const float* __restrict__ obj_pos,
                                              const int* __restrict__ nuc,
                                              const int* __restrict__ central,
                                              const int* __restrict__ backbone,
                                              const int* __restrict__ obj_batch,
                                              const float* __restrict__ Wn,
                                              const float* __restrict__ bn,
                                              float* __restrict__ sums,
                                              float* __restrict__ cnt) {
    __shared__ float ls[GG * HH];
    __shared__ float lc[GG];
    int t = threadIdx.x;
    for (int i = t; i < GG * HH; i += 256) ls[i] = 0.f;
    if (t < GG) lc[t] = 0.f;
    __syncthreads();
    int col = t & 127;
    int sub = t >> 7;  // 0..1
    int base = blockIdx.x * 32;
    for (int it = 0; it < 16; it++) {
        int o = base + it * 2 + sub;
        int nv = nuc[o];
        bool isb = (backbone[o] == 0);
        bool cond = (nv == 0) || ((central[o] != 0) && isb) || ((nv == 2) && isb);
        if (cond) {
            float acc = bn[col];
#pragma unroll
            for (int k = 0; k < 13; k++) acc += obj_x[o * 13 + k] * Wn[k * HH + col];
#pragma unroll
            for (int k = 0; k < 3; k++) acc += obj_pos[o * 3 + k] * Wn[(13 + k) * HH + col];
            int g = obj_batch[o];
            atomicAdd(&ls[g * HH + col], acc);
            if (col == 0) atomicAdd(&lc[g], 1.f);
        }
    }
    __syncthreads();
    for (int i = t; i < GG * HH; i += 256) atomicAdd(&sums[i], ls[i]);
    if (t < GG) atomicAdd(&cnt[t], lc[t]);
}

// ---------------- add_h = time_h + cond_h  (single block, 1024 thr) ----------------
__global__ __launch_bounds__(1024) void k_addh(const int* __restrict__ timestep,
                                               const float* __restrict__ sums,
                                               const float* __restrict__ cnt,
                                               const float* __restrict__ Wt,
                                               const float* __restrict__ bt,
                                               const float* __restrict__ Wc,
                                               const float* __restrict__ bc,
                                               float* __restrict__ add_h) {
    __shared__ float te[GG * HH];
    __shared__ float pl[GG * HH];
    int t = threadIdx.x;
    int g = t >> 7, j = t & 127;
    float tv = (float)timestep[g];
    float v;
    if (j < 64) {
        float f = expf(-logf(10000.f) * (float)j / 64.f);
        v = cosf(tv * f);
    } else {
        float f = expf(-logf(10000.f) * (float)(j - 64) / 64.f);
        v = sinf(tv * f);
    }
    te[t] = v;
    pl[t] = sums[t] / fmaxf(cnt[g], 1.f);
    __syncthreads();
    float acc = bt[j] + bc[j];
    for (int k = 0; k < HH; k++) {
        acc += te[g * HH + k] * Wt[k * HH + j] + pl[g * HH + k] * Wc[k * HH + j];
    }
    add_h[t] = acc;
}

// ---------------- in-degree count ----------------
__global__ void k_deg(const int* __restrict__ dst, int* __restrict__ deg) {
    int e = blockIdx.x * 256 + threadIdx.x;
    if (e < EE) atomicAdd(&deg[dst[e]], 1);
}

// ---------------- exclusive scan (1 block, 1024 thr, 4 elems each) + dinv ----------------
__global__ __launch_bounds__(1024) void k_scan(const int* __restrict__ deg,
                                               int* __restrict__ row_ptr,
                                               int* __restrict__ cursor,
                                               float* __restrict__ dinv) {
    __shared__ int aux[1024];
    int t = threadIdx.x;
    int d[4];
    int s = 0;
#pragma unroll
    for (int i = 0; i < 4; i++) {
        d[i] = deg[t * 4 + i];
        s += d[i];
    }
    aux[t] = s;
    __syncthreads();
    for (int off = 1; off < 1024; off <<= 1) {
        int v = (t >= off) ? aux[t - off] : 0;
        __syncthreads();
        aux[t] += v;
        __syncthreads();
    }
    int run = (t > 0) ? aux[t - 1] : 0;
#pragma unroll
    for (int i = 0; i < 4; i++) {
        int idx = t * 4 + i;
        row_ptr[idx] = run;
        cursor[idx] = run;
        dinv[idx] = rsqrtf((float)(d[i] + 1));  // +1: self loop
        run += d[i];
    }
    if (t == 1023) row_ptr[NN] = run;
}

// ---------------- scatter edges into CSR ----------------
__global__ void k_scatter(const int* __restrict__ src, const int* __restrict__ dst,
                          int* __restrict__ cursor, int* __restrict__ col_idx) {
    int e = blockIdx.x * 256 + threadIdx.x;
    if (e < EE) {
        int pos = atomicAdd(&cursor[dst[e]], 1);
        col_idx[pos] = src[e];
    }
}

// ---------------- xw = (A [+ add_h[batch_map]]) @ W  (128x128) ----------------
__global__ __launch_bounds__(128) void k_gemm_h(const float* __restrict__ A,
                                                const float* __restrict__ W,
                                                float* __restrict__ out,
                                                const float* __restrict__ addv,
                                                const int* __restrict__ bm) {
    __shared__ float At[8][HH];
    int r0 = blockIdx.x * 8;
    int t = threadIdx.x;  // 128
#pragma unroll
    for (int r = 0; r < 8; r++) {
        float v = A[(r0 + r) * HH + t];
        if (addv) v += addv[bm[r0 + r] * HH + t];
        At[r][t] = v;
    }
    __syncthreads();
    float acc[8] = {0, 0, 0, 0, 0, 0, 0, 0};
    for (int k = 0; k < HH; k++) {
        float w = W[k * HH + t];
#pragma unroll
        for (int r = 0; r < 8; r++) acc[r] += At[r][k] * w;
    }
#pragma unroll
    for (int r = 0; r < 8; r++) out[(r0 + r) * HH + t] = acc[r];
}

// ---------------- GCN aggregation: out = relu(dinv[dst]*(sum + self) + b) ----------------
__global__ __launch_bounds__(128) void k_agg(const float* __restrict__ xw,
                                             const int* __restrict__ row_ptr,
                                             const int* __restrict__ col_idx,
                                             const float* __restrict__ dinv,
                                             const float* __restrict__ bias,
                                             float* __restrict__ out) {
    int dst = blockIdx.x;
    int t = threadIdx.x;  // 128
    float dd = dinv[dst];
    float acc = xw[dst * HH + t] * dd;  // self loop
    int beg = row_ptr[dst], end = row_ptr[dst + 1];
    for (int e = beg; e < end; e++) {
        int s = col_idx[e];
        acc += xw[s * HH + t] * dinv[s];
    }
    float v = dd * acc + bias[t];
    out[dst * HH + t] = fmaxf(v, 0.f);
}

// ---------------- node_noise_pred = h @ W_out + b_out -> fp32 ----------------
__global__ __launch_bounds__(256) void k_pred(const float* __restrict__ h,
                                              const float* __restrict__ Wo,
                                              const float* __restrict__ bo,
                                              float* __restrict__ outp) {
    int idx = blockIdx.x * 256 + threadIdx.x;  // 65536
    int row = idx >> 4, c = idx & 15;
    float acc = bo[c];
    for (int k = 0; k < HH; k++) acc += h[row * HH + k] * Wo[k * NDD + c];
    outp[idx] = acc;
}

// ---------------- s_l / s_r (one wave per row) ----------------
__global__ __launch_bounds__(256) void k_slr(const float* __restrict__ h,
                                             const float* __restrict__ we,
                                             float* __restrict__ sl,
                                             float* __restrict__ sr) {
    int row = blockIdx.x * 4 + (threadIdx.x >> 6);
    int l = threadIdx.x & 63;
    float a0 = h[row * HH + l], a1 = h[row * HH + 64 + l];
    float pl = a0 * we[l] + a1 * we[64 + l];
    float pr = a0 * we[HH + l] + a1 * we[HH + 64 + l];
    for (int off = 32; off; off >>= 1) {
        pl += __shfl_down(pl, off);
        pr += __shfl_down(pr, off);
    }
    if (l == 0) {
        sl[row] = pl;
        sr[row] = pr;
    }
}

// ---------------- edge logits: rows b and NN-2-b per block (4096 elems) -> fp32 ----------------
__global__ __launch_bounds__(256) void k_edges(const float* __restrict__ sl,
                                               const float* __restrict__ sr,
                                               const float* __restrict__ be_p,
                                               float* __restrict__ out) {
    int b = blockIdx.x;
    float be = be_p[0];
    int t = threadIdx.x;
#pragma unroll
    for (int half = 0; half < 2; half++) {
        int r = half == 0 ? b : (NN - 2 - b);
        long long off = (long long)r * (2LL * NN - r - 1) / 2;
        float s = sl[r] + be;
        int len = NN - 1 - r;
        const float* srp = sr + r + 1;
        float* op = out + off;
        for (int i = t; i < len; i += 256) op[i] = s + srp[i];
    }
}

extern "C" void kernel_launch(void* const* d_in, const int* in_sizes, int n_in,
                              void* d_out, int out_size, void* d_ws, size_t ws_size,
                              hipStream_t stream) {
    const float* x = (const float*)d_in[0];
    const int* edge = (const int*)d_in[1];  // src = edge, dst = edge + EE
    const int* timestep = (const int*)d_in[2];
    const int* batch_map = (const int*)d_in[3];
    const int* nuc = (const int*)d_in[4];
    const int* central = (const int*)d_in[5];
    const int* backbone = (const int*)d_in[6];
    const float* obj_x = (const float*)d_in[7];
    const float* obj_pos = (const float*)d_in[8];
    const int* obj_batch = (const int*)d_in[9];
    const float* W_node = (const float*)d_in[10];
    const float* b_node = (const float*)d_in[11];
    const float* W_cond = (const float*)d_in[12];
    const float* b_cond = (const float*)d_in[13];
    const float* W_time = (const float*)d_in[14];
    const float* b_time = (const float*)d_in[15];
    const float* W_conv1 = (const float*)d_in[16];
    const float* b_conv1 = (const float*)d_in[17];
    const float* W_conv2 = (const float*)d_in[18];
    const float* b_conv2 = (const float*)d_in[19];
    const float* W_out = (const float*)d_in[20];
    const float* b_out = (const float*)d_in[21];
    const float* w_edge = (const float*)d_in[22];
    const float* b_edge = (const float*)d_in[23];

    const int* e_src = edge;
    const int* e_dst = edge + EE;

    // workspace layout (fp32 / int32, all 4B aligned)
    float* ws = (float*)d_ws;
    float* bufA = ws;                 // N*H  (node_emb_base, later xw2)
    float* bufB = bufA + NN * HH;     // N*H  (xw1, later h2)
    float* bufC = bufB + NN * HH;     // N*H  (h1)
    float* sums = bufC + NN * HH;     // G*H
    float* cnt = sums + GG * HH;      // G
    float* add_h = cnt + GG;          // G*H
    float* dinv = add_h + GG * HH;    // N
    float* sl = dinv + NN;            // N
    float* sr = sl + NN;              // N
    int* deg = (int*)(sr + NN);       // N
    int* row_ptr = deg + NN;          // N+1
    int* cursor = row_ptr + NN + 1;   // N
    int* col_idx = cursor + NN;       // E

    float* out_pred = (float*)d_out;
    float* out_edges = out_pred + NN * NDD;

    // 0. init accumulators
    k_init<<<(NN + 255) / 256, 256, 0, stream>>>(deg, sums, cnt);
    // 1. node_emb_base -> bufA
    k_node_emb<<<NN / 8, 128, 0, stream>>>(x, W_node, b_node, bufA);
    // 2. cond pooling partials
    k_cond<<<MM / 32, 256, 0, stream>>>(obj_x, obj_pos, nuc, central, backbone,
                                        obj_batch, W_node, b_node, sums, cnt);
    // 3. degrees
    k_deg<<<EE / 256, 256, 0, stream>>>(e_dst, deg);
    // 4. add_h = time_h + cond_h
    k_addh<<<1, 1024, 0, stream>>>(timestep, sums, cnt, W_time, b_time, W_cond,
                                   b_cond, add_h);
    // 5. scan -> row_ptr/cursor/dinv
    k_scan<<<1, 1024, 0, stream>>>(deg, row_ptr, cursor, dinv);
    // 6. CSR scatter
    k_scatter<<<EE / 256, 256, 0, stream>>>(e_src, e_dst, cursor, col_idx);
    // 7. conv1 GEMM (fused node_emb + add_h[batch_map]) -> bufB
    k_gemm_h<<<NN / 8, 128, 0, stream>>>(bufA, W_conv1, bufB, add_h, batch_map);
    // 8. conv1 aggregation -> bufC (h1)
    k_agg<<<NN, 128, 0, stream>>>(bufB, row_ptr, col_idx, dinv, b_conv1, bufC);
    // 9. conv2 GEMM -> bufA (xw2)
    k_gemm_h<<<NN / 8, 128, 0, stream>>>(bufC, W_conv2, bufA, nullptr, nullptr);
    // 10. conv2 aggregation -> bufB (h2)
    k_agg<<<NN, 128, 0, stream>>>(bufA, row_ptr, col_idx, dinv, b_conv2, bufB);
    // 11. node_noise_pred head
    k_pred<<<NN * NDD / 256, 256, 0, stream>>>(bufB, W_out, b_out, out_pred);
    // 12. s_l / s_r
    k_slr<<<NN / 4, 256, 0, stream>>>(bufB, w_edge, sl, sr);
    // 13. edge logits
    k_edges<<<NN / 2, 256, 0, stream>>>(sl, sr, b_edge, out_edges);
}